// Round 1
// baseline (352.682 us; speedup 1.0000x reference)
//
#include <hip/hip_runtime.h>
#include <cstdint>
#include <cstddef>

// Problem constants (fixed by the reference)
#define B_DIM 8192
#define C_DIM 4096
#define F_DIM 1024
#define O_DIM 10

typedef __attribute__((ext_vector_type(8))) __bf16 bf16x8;
typedef __attribute__((ext_vector_type(8))) unsigned short ushort8;
typedef __attribute__((ext_vector_type(4))) float f32x4;

// ---------------------------------------------------------------------------
// fp32 -> bf16 round-to-nearest-even
__device__ __forceinline__ unsigned short f2bf(float f) {
  unsigned int u = __builtin_bit_cast(unsigned int, f);
  u += 0x7fffu + ((u >> 16) & 1u);
  return (unsigned short)(u >> 16);
}

// ---------------------------------------------------------------------------
// Per-row: convert fp32 row (F_DIM elems) to bf16, compute fp32 sum of squares.
// One block (256 threads) per row; each thread handles exactly one float4.
__global__ __launch_bounds__(256) void prep_rows(const float* __restrict__ src,
                                                 unsigned short* __restrict__ dst,
                                                 float* __restrict__ norms) {
  const int row = blockIdx.x;
  const int t = threadIdx.x;
  const float4 v = reinterpret_cast<const float4*>(src + (size_t)row * F_DIM)[t];
  float ss = v.x * v.x + v.y * v.y + v.z * v.z + v.w * v.w;
  ushort4 o;
  o.x = f2bf(v.x); o.y = f2bf(v.y); o.z = f2bf(v.z); o.w = f2bf(v.w);
  reinterpret_cast<ushort4*>(dst + (size_t)row * F_DIM)[t] = o;
#pragma unroll
  for (int m = 1; m <= 32; m <<= 1) ss += __shfl_xor(ss, m, 64);
  __shared__ float red[4];
  if ((t & 63) == 0) red[t >> 6] = ss;
  __syncthreads();
  if (t == 0) norms[row] = red[0] + red[1] + red[2] + red[3];
}

// neg inverse scale
__global__ __launch_bounds__(256) void prep_scale(const float* __restrict__ s,
                                                  float* __restrict__ nis, int n) {
  int i = blockIdx.x * 256 + threadIdx.x;
  if (i < n) nis[i] = -1.0f / s[i];
}

// ---------------------------------------------------------------------------
// Fused: S = loc_bf16 @ x_bf16^T (MFMA), phi = exp(-sqrt(max(c2+x2-2S,0))/scale),
// out[b][o] += sum_c phi[c][b] * w[o][c]  (atomic).
//
// Tile: 128 centroids (M) x 128 batch (N), BK=32. 4 waves in 2x2 arrangement,
// each wave 64x64 via 4x4 grid of 16x16x32 MFMAs.
// A = loc rows are [c][k] (k-contiguous), B^T = x rows are [b][k] (k-contiguous):
// both operands load as row[lane&15], k = quad*8..+7 (ds_read_b128).
__global__ __launch_bounds__(256, 2) void rbf_fused(
    const unsigned short* __restrict__ locb,  // [C_DIM][F_DIM] bf16 bits
    const unsigned short* __restrict__ xb,    // [B_DIM][F_DIM] bf16 bits
    const float* __restrict__ c2,             // [C_DIM]
    const float* __restrict__ x2,             // [B_DIM]
    const float* __restrict__ nis,            // [C_DIM]  (-1/scale)
    const float* __restrict__ w,              // [O_DIM][C_DIM]
    float* __restrict__ out) {                // [B_DIM][O_DIM], pre-zeroed
  __shared__ alignas(16) unsigned short As[128 * 32];  // loc tile [c][k]
  __shared__ alignas(16) unsigned short Bs[128 * 32];  // x tile   [b][k]

  const int tid = threadIdx.x;
  const int wave = tid >> 6;
  const int lane = tid & 63;
  const int quad = lane >> 4;
  const int n15 = lane & 15;

  const int cBase = blockIdx.y * 128;
  const int bBase = blockIdx.x * 128;
  const int wc = (wave >> 1) * 64;  // wave's centroid offset within tile
  const int wb = (wave & 1) * 64;   // wave's batch offset within tile

  // Staging: tile = 8 KiB = 8 chunks of 1024 B; wave handles chunks {wave, wave+4}.
  // Within a chunk (16 rows x 64 B): lane l -> row l>>2, byte (l&3)*16.
  const int rows0 = wave * 16 + (lane >> 2);
  const int rows1 = (wave + 4) * 16 + (lane >> 2);
  const int colOff = (lane & 3) * 8;  // bf16 elements

  const unsigned short* gA0 = locb + (size_t)(cBase + rows0) * F_DIM + colOff;
  const unsigned short* gA1 = locb + (size_t)(cBase + rows1) * F_DIM + colOff;
  const unsigned short* gB0 = xb + (size_t)(bBase + rows0) * F_DIM + colOff;
  const unsigned short* gB1 = xb + (size_t)(bBase + rows1) * F_DIM + colOff;
  unsigned short* lA0 = &As[wave * 512];        // wave-uniform LDS bases
  unsigned short* lA1 = &As[(wave + 4) * 512];
  unsigned short* lB0 = &Bs[wave * 512];
  unsigned short* lB1 = &Bs[(wave + 4) * 512];

  f32x4 acc[4][4];
  const f32x4 zero = {0.f, 0.f, 0.f, 0.f};
#pragma unroll
  for (int i = 0; i < 4; ++i)
#pragma unroll
    for (int j = 0; j < 4; ++j) acc[i][j] = zero;

  for (int k0 = 0; k0 < F_DIM; k0 += 32) {
    __builtin_amdgcn_global_load_lds(
        (const __attribute__((address_space(1))) void*)(gA0 + k0),
        (__attribute__((address_space(3))) void*)lA0, 16, 0, 0);
    __builtin_amdgcn_global_load_lds(
        (const __attribute__((address_space(1))) void*)(gA1 + k0),
        (__attribute__((address_space(3))) void*)lA1, 16, 0, 0);
    __builtin_amdgcn_global_load_lds(
        (const __attribute__((address_space(1))) void*)(gB0 + k0),
        (__attribute__((address_space(3))) void*)lB0, 16, 0, 0);
    __builtin_amdgcn_global_load_lds(
        (const __attribute__((address_space(1))) void*)(gB1 + k0),
        (__attribute__((address_space(3))) void*)lB1, 16, 0, 0);
    __syncthreads();

    bf16x8 af[4], bfr[4];
#pragma unroll
    for (int ti = 0; ti < 4; ++ti)
      af[ti] = __builtin_bit_cast(
          bf16x8, *(const ushort8*)&As[(wc + ti * 16 + n15) * 32 + quad * 8]);
#pragma unroll
    for (int tj = 0; tj < 4; ++tj)
      bfr[tj] = __builtin_bit_cast(
          bf16x8, *(const ushort8*)&Bs[(wb + tj * 16 + n15) * 32 + quad * 8]);

#pragma unroll
    for (int ti = 0; ti < 4; ++ti)
#pragma unroll
      for (int tj = 0; tj < 4; ++tj)
        acc[ti][tj] = __builtin_amdgcn_mfma_f32_16x16x32_bf16(
            af[ti], bfr[tj], acc[ti][tj], 0, 0, 0);
    __syncthreads();
  }

  // ---- epilogue ----
  // acc[ti][tj][r]: S at centroid c = cBase+wc+ti*16+quad*4+r,
  //                 batch    b = bBase+wb+tj*16+n15.
  float x2v[4];
#pragma unroll
  for (int tj = 0; tj < 4; ++tj) x2v[tj] = x2[bBase + wb + tj * 16 + n15];

  float partial[4][O_DIM];
#pragma unroll
  for (int tj = 0; tj < 4; ++tj)
#pragma unroll
    for (int o = 0; o < O_DIM; ++o) partial[tj][o] = 0.f;

#pragma unroll
  for (int ti = 0; ti < 4; ++ti) {
#pragma unroll
    for (int r = 0; r < 4; ++r) {
      const int c = cBase + wc + ti * 16 + quad * 4 + r;
      const float c2v = c2[c];
      const float ns = nis[c];
      float phi[4];
#pragma unroll
      for (int tj = 0; tj < 4; ++tj) {
        const float s = acc[ti][tj][r];
        const float sq = fmaxf(x2v[tj] + c2v - 2.0f * s, 0.0f);
        phi[tj] = __expf(sqrtf(sq) * ns);
      }
#pragma unroll
      for (int o = 0; o < O_DIM; ++o) {
        const float wv = w[o * C_DIM + c];
#pragma unroll
        for (int tj = 0; tj < 4; ++tj)
          partial[tj][o] = fmaf(phi[tj], wv, partial[tj][o]);
      }
    }
  }

  // reduce over the 4 quads (lanes ^16, ^32 share the same batch index)
#pragma unroll
  for (int tj = 0; tj < 4; ++tj)
#pragma unroll
    for (int o = 0; o < O_DIM; ++o) {
      float v = partial[tj][o];
      v += __shfl_xor(v, 16, 64);
      v += __shfl_xor(v, 32, 64);
      partial[tj][o] = v;
    }

  if (quad == 0) {
#pragma unroll
    for (int tj = 0; tj < 4; ++tj) {
      const int b = bBase + wb + tj * 16 + n15;
#pragma unroll
      for (int o = 0; o < O_DIM; ++o)
        atomicAdd(&out[b * O_DIM + o], partial[tj][o]);
    }
  }
}

// ---------------------------------------------------------------------------
extern "C" void kernel_launch(void* const* d_in, const int* in_sizes, int n_in,
                              void* d_out, int out_size, void* d_ws, size_t ws_size,
                              hipStream_t stream) {
  const float* x = (const float*)d_in[0];      // [8192,1024]
  const float* loc = (const float*)d_in[1];    // [4096,1024]
  const float* scale = (const float*)d_in[2];  // [4096]
  const float* w = (const float*)d_in[3];      // [10,4096]
  float* out = (float*)d_out;                  // [8192,10]

  // workspace layout (~24.1 MB)
  char* ws = (char*)d_ws;
  unsigned short* xb = (unsigned short*)(ws);                       // 16 MB
  unsigned short* locb = (unsigned short*)(ws + (size_t)16 * 1024 * 1024);  // 8 MB
  float* x2 = (float*)(ws + (size_t)24 * 1024 * 1024);              // 32 KB
  float* c2 = (float*)(ws + (size_t)24 * 1024 * 1024 + 64 * 1024);  // 16 KB
  float* nis = (float*)(ws + (size_t)24 * 1024 * 1024 + 96 * 1024); // 16 KB

  hipMemsetAsync(d_out, 0, (size_t)out_size * sizeof(float), stream);
  prep_rows<<<B_DIM, 256, 0, stream>>>(x, xb, x2);
  prep_rows<<<C_DIM, 256, 0, stream>>>(loc, locb, c2);
  prep_scale<<<(C_DIM + 255) / 256, 256, 0, stream>>>(scale, nis, C_DIM);

  dim3 grid(B_DIM / 128, C_DIM / 128);  // (64, 32)
  rbf_fused<<<grid, 256, 0, stream>>>(locb, xb, c2, x2, nis, w, out);
}

// Round 2
// 230.971 us; speedup vs baseline: 1.5270x; 1.5270x over previous
//
#include <hip/hip_runtime.h>
#include <cstdint>
#include <cstddef>

// Problem constants (fixed by the reference)
#define B_DIM 8192
#define C_DIM 4096
#define F_DIM 1024
#define O_DIM 10
#define NCBLK 32  // C_DIM / 128 split-K-style partial slices

typedef __attribute__((ext_vector_type(8))) __bf16 bf16x8;
typedef __attribute__((ext_vector_type(8))) unsigned short ushort8;
typedef __attribute__((ext_vector_type(4))) float f32x4;

// ---------------------------------------------------------------------------
// fp32 -> bf16 round-to-nearest-even
__device__ __forceinline__ unsigned short f2bf(float f) {
  unsigned int u = __builtin_bit_cast(unsigned int, f);
  u += 0x7fffu + ((u >> 16) & 1u);
  return (unsigned short)(u >> 16);
}

// ---------------------------------------------------------------------------
// Per-row: convert fp32 row (F_DIM elems) to bf16, compute fp32 sum of squares.
__global__ __launch_bounds__(256) void prep_rows(const float* __restrict__ src,
                                                 unsigned short* __restrict__ dst,
                                                 float* __restrict__ norms) {
  const int row = blockIdx.x;
  const int t = threadIdx.x;
  const float4 v = reinterpret_cast<const float4*>(src + (size_t)row * F_DIM)[t];
  float ss = v.x * v.x + v.y * v.y + v.z * v.z + v.w * v.w;
  ushort4 o;
  o.x = f2bf(v.x); o.y = f2bf(v.y); o.z = f2bf(v.z); o.w = f2bf(v.w);
  reinterpret_cast<ushort4*>(dst + (size_t)row * F_DIM)[t] = o;
#pragma unroll
  for (int m = 1; m <= 32; m <<= 1) ss += __shfl_xor(ss, m, 64);
  __shared__ float red[4];
  if ((t & 63) == 0) red[t >> 6] = ss;
  __syncthreads();
  if (t == 0) norms[row] = red[0] + red[1] + red[2] + red[3];
}

// neg inverse scale
__global__ __launch_bounds__(256) void prep_scale(const float* __restrict__ s,
                                                  float* __restrict__ nis, int n) {
  int i = blockIdx.x * 256 + threadIdx.x;
  if (i < n) nis[i] = -1.0f / s[i];
}

// ---------------------------------------------------------------------------
// Fused: S = loc_bf16 @ x_bf16^T (MFMA), phi = exp(-sqrt(max(c2+x2-2S,0))/scale),
// P[cblk][b][o] = sum_{c in block} phi[c][b] * w[o][c]   (no atomics).
//
// Tile: 128 centroids (M) x 128 batch (N), BK=32; 4 waves 2x2; wave = 64x64
// via 4x4 grid of 16x16x32 MFMAs.
//
// LDS k-chunk XOR swizzle: logical 16B chunk q of row r lives at physical
// slot q ^ ((r&15)>>1 & 3). global_load_lds forces LDS dest = base + lane*16,
// so the *global source* chunk is permuted at staging time instead.
__global__ __launch_bounds__(256, 4) void rbf_fused(
    const unsigned short* __restrict__ locb,  // [C_DIM][F_DIM] bf16 bits
    const unsigned short* __restrict__ xb,    // [B_DIM][F_DIM] bf16 bits
    const float* __restrict__ c2,             // [C_DIM]
    const float* __restrict__ x2,             // [B_DIM]
    const float* __restrict__ nis,            // [C_DIM]  (-1/scale)
    const float* __restrict__ w,              // [O_DIM][C_DIM]
    float* __restrict__ P) {                  // [NCBLK][B_DIM][O_DIM]
  __shared__ alignas(16) unsigned short As[128 * 32];  // loc tile [c][k] 8KB
  __shared__ alignas(16) unsigned short Bs[128 * 32];  // x tile   [b][k] 8KB
  __shared__ alignas(16) float wlds[O_DIM * 128];      // w tile 5KB
  __shared__ float c2l[128];
  __shared__ float nisl[128];

  const int tid = threadIdx.x;
  const int wave = tid >> 6;
  const int lane = tid & 63;
  const int quad = lane >> 4;
  const int n15 = lane & 15;

  const int cBase = blockIdx.y * 128;
  const int bBase = blockIdx.x * 128;
  const int wc = (wave >> 1) * 64;  // wave's centroid offset within tile
  const int wb = (wave & 1) * 64;   // wave's batch offset within tile

  // Stage epilogue operands (visible by first __syncthreads in K-loop).
  for (int i = tid; i < O_DIM * 128; i += 256)
    wlds[i] = w[(i >> 7) * C_DIM + cBase + (i & 127)];
  if (tid < 128) {
    c2l[tid] = c2[cBase + tid];
    nisl[tid] = nis[cBase + tid];
  }

  // Staging: tile = 8KB = 8 chunks of 1024B; wave handles chunks {wave, wave+4}.
  // Within a chunk (16 rows x 64B): lane l -> row l>>2; physical slot l&3;
  // fetch global chunk (l&3) ^ g(row), g(r) = (r>>1)&3.
  const int rows0 = wave * 16 + (lane >> 2);
  const int rows1 = (wave + 4) * 16 + (lane >> 2);
  const int colOff = (((lane & 3) ^ ((lane >> 3) & 3))) * 8;  // bf16 elems

  const unsigned short* gA0 = locb + (size_t)(cBase + rows0) * F_DIM + colOff;
  const unsigned short* gA1 = locb + (size_t)(cBase + rows1) * F_DIM + colOff;
  const unsigned short* gB0 = xb + (size_t)(bBase + rows0) * F_DIM + colOff;
  const unsigned short* gB1 = xb + (size_t)(bBase + rows1) * F_DIM + colOff;
  unsigned short* lA0 = &As[wave * 512];  // wave-uniform LDS bases
  unsigned short* lA1 = &As[(wave + 4) * 512];
  unsigned short* lB0 = &Bs[wave * 512];
  unsigned short* lB1 = &Bs[(wave + 4) * 512];

  // Reader chunk swizzle: row within 16-row chunk is n15.
  const int swA = (quad ^ ((n15 >> 1) & 3)) * 8;  // halfs

  f32x4 acc[4][4];
  const f32x4 zero = {0.f, 0.f, 0.f, 0.f};
#pragma unroll
  for (int i = 0; i < 4; ++i)
#pragma unroll
    for (int j = 0; j < 4; ++j) acc[i][j] = zero;

  for (int k0 = 0; k0 < F_DIM; k0 += 32) {
    __builtin_amdgcn_global_load_lds(
        (const __attribute__((address_space(1))) void*)(gA0 + k0),
        (__attribute__((address_space(3))) void*)lA0, 16, 0, 0);
    __builtin_amdgcn_global_load_lds(
        (const __attribute__((address_space(1))) void*)(gA1 + k0),
        (__attribute__((address_space(3))) void*)lA1, 16, 0, 0);
    __builtin_amdgcn_global_load_lds(
        (const __attribute__((address_space(1))) void*)(gB0 + k0),
        (__attribute__((address_space(3))) void*)lB0, 16, 0, 0);
    __builtin_amdgcn_global_load_lds(
        (const __attribute__((address_space(1))) void*)(gB1 + k0),
        (__attribute__((address_space(3))) void*)lB1, 16, 0, 0);
    __syncthreads();

    bf16x8 af[4], bfr[4];
#pragma unroll
    for (int ti = 0; ti < 4; ++ti)
      af[ti] = __builtin_bit_cast(
          bf16x8, *(const ushort8*)&As[(wc + ti * 16 + n15) * 32 + swA]);
#pragma unroll
    for (int tj = 0; tj < 4; ++tj)
      bfr[tj] = __builtin_bit_cast(
          bf16x8, *(const ushort8*)&Bs[(wb + tj * 16 + n15) * 32 + swA]);

#pragma unroll
    for (int ti = 0; ti < 4; ++ti)
#pragma unroll
      for (int tj = 0; tj < 4; ++tj)
        acc[ti][tj] = __builtin_amdgcn_mfma_f32_16x16x32_bf16(
            af[ti], bfr[tj], acc[ti][tj], 0, 0, 0);
    __syncthreads();
  }

  // ---- epilogue ----
  // acc[ti][tj][r]: S at c_local = wc+ti*16+quad*4+r, b_local = wb+tj*16+n15.
  float x2v[4];
#pragma unroll
  for (int tj = 0; tj < 4; ++tj) x2v[tj] = x2[bBase + wb + tj * 16 + n15];

  float partial[4][O_DIM];
#pragma unroll
  for (int tj = 0; tj < 4; ++tj)
#pragma unroll
    for (int o = 0; o < O_DIM; ++o) partial[tj][o] = 0.f;

#pragma unroll
  for (int ti = 0; ti < 4; ++ti) {
    const int clq = wc + ti * 16 + quad * 4;
    const f32x4 c24 = *(const f32x4*)&c2l[clq];
    const f32x4 ns4 = *(const f32x4*)&nisl[clq];
    float phi[4][4];  // [tj][r]
#pragma unroll
    for (int tj = 0; tj < 4; ++tj)
#pragma unroll
      for (int r = 0; r < 4; ++r) {
        const float s = acc[ti][tj][r];
        const float sq = fmaxf(x2v[tj] + c24[r] - 2.0f * s, 0.0f);
        phi[tj][r] = __expf(sqrtf(sq) * ns4[r]);
      }
#pragma unroll
    for (int o = 0; o < O_DIM; ++o) {
      const f32x4 w4 = *(const f32x4*)&wlds[o * 128 + clq];
#pragma unroll
      for (int tj = 0; tj < 4; ++tj)
#pragma unroll
        for (int r = 0; r < 4; ++r)
          partial[tj][o] = fmaf(phi[tj][r], w4[r], partial[tj][o]);
    }
  }

  // reduce over the 4 quads (lanes ^16, ^32 share the same batch index)
#pragma unroll
  for (int tj = 0; tj < 4; ++tj)
#pragma unroll
    for (int o = 0; o < O_DIM; ++o) {
      float v = partial[tj][o];
      v += __shfl_xor(v, 16, 64);
      v += __shfl_xor(v, 32, 64);
      partial[tj][o] = v;
    }

  // Block-level reduce across the two wc halves via LDS (alias dead As tile),
  // then one plain coalesced store per (b,o) — no atomics.
  float* red = reinterpret_cast<float*>(As);  // 1280 floats needed, 8KB avail
  if (wc == 0 && quad == 0) {
#pragma unroll
    for (int tj = 0; tj < 4; ++tj)
#pragma unroll
      for (int o = 0; o < O_DIM; ++o)
        red[(wb + tj * 16 + n15) * O_DIM + o] = partial[tj][o];
  }
  __syncthreads();
  if (wc == 64 && quad == 0) {
#pragma unroll
    for (int tj = 0; tj < 4; ++tj)
#pragma unroll
      for (int o = 0; o < O_DIM; ++o)
        red[(wb + tj * 16 + n15) * O_DIM + o] += partial[tj][o];
  }
  __syncthreads();
  float* Pdst = P + (size_t)blockIdx.y * (B_DIM * O_DIM) + (size_t)bBase * O_DIM;
  for (int i = tid; i < 128 * O_DIM; i += 256) Pdst[i] = red[i];
}

// ---------------------------------------------------------------------------
// out[b][o] = sum_k P[k][b][o]
__global__ __launch_bounds__(256) void reduce_partials(const float* __restrict__ P,
                                                       float* __restrict__ out) {
  const int i = blockIdx.x * 256 + threadIdx.x;  // 0 .. B_DIM*O_DIM-1
  float s = 0.f;
#pragma unroll 8
  for (int k = 0; k < NCBLK; ++k) s += P[(size_t)k * (B_DIM * O_DIM) + i];
  out[i] = s;
}

// ---------------------------------------------------------------------------
extern "C" void kernel_launch(void* const* d_in, const int* in_sizes, int n_in,
                              void* d_out, int out_size, void* d_ws, size_t ws_size,
                              hipStream_t stream) {
  const float* x = (const float*)d_in[0];      // [8192,1024]
  const float* loc = (const float*)d_in[1];    // [4096,1024]
  const float* scale = (const float*)d_in[2];  // [4096]
  const float* w = (const float*)d_in[3];      // [10,4096]
  float* out = (float*)d_out;                  // [8192,10]

  // workspace layout (~35.6 MB)
  char* ws = (char*)d_ws;
  unsigned short* xb = (unsigned short*)(ws);                              // 16 MB
  unsigned short* locb = (unsigned short*)(ws + (size_t)16 * 1024 * 1024); // 8 MB
  float* x2 = (float*)(ws + (size_t)24 * 1024 * 1024);                    // 32 KB
  float* c2 = (float*)(ws + (size_t)24 * 1024 * 1024 + 64 * 1024);        // 16 KB
  float* nis = (float*)(ws + (size_t)24 * 1024 * 1024 + 96 * 1024);       // 16 KB
  float* P = (float*)(ws + (size_t)25 * 1024 * 1024);                     // 10.5 MB

  prep_rows<<<B_DIM, 256, 0, stream>>>(x, xb, x2);
  prep_rows<<<C_DIM, 256, 0, stream>>>(loc, locb, c2);
  prep_scale<<<(C_DIM + 255) / 256, 256, 0, stream>>>(scale, nis, C_DIM);

  dim3 grid(B_DIM / 128, C_DIM / 128);  // (64, 32)
  rbf_fused<<<grid, 256, 0, stream>>>(locb, xb, c2, x2, nis, w, P);

  reduce_partials<<<(B_DIM * O_DIM) / 256, 256, 0, stream>>>(P, out);
}

// Round 3
// 197.729 us; speedup vs baseline: 1.7837x; 1.1681x over previous
//
#include <hip/hip_runtime.h>
#include <cstdint>
#include <cstddef>

// Problem constants (fixed by the reference)
#define B_DIM 8192
#define C_DIM 4096
#define F_DIM 1024
#define O_DIM 10
#define NSLICE 16  // C_DIM / 256 partial slices

typedef __attribute__((ext_vector_type(8))) __bf16 bf16x8;
typedef __attribute__((ext_vector_type(8))) unsigned short ushort8;
typedef __attribute__((ext_vector_type(4))) float f32x4;

// ---------------------------------------------------------------------------
// fp32 -> bf16 round-to-nearest-even
__device__ __forceinline__ unsigned short f2bf(float f) {
  unsigned int u = __builtin_bit_cast(unsigned int, f);
  u += 0x7fffu + ((u >> 16) & 1u);
  return (unsigned short)(u >> 16);
}

// ---------------------------------------------------------------------------
// Merged prep: rows [0,B_DIM) convert x, rows [B_DIM, B_DIM+C_DIM) convert loc.
// Converts fp32 row -> bf16 and computes fp32 ||row||^2.
__global__ __launch_bounds__(256) void prep_merged(
    const float* __restrict__ x, const float* __restrict__ loc,
    unsigned short* __restrict__ xb, unsigned short* __restrict__ locb,
    float* __restrict__ x2, float* __restrict__ c2) {
  const int row = blockIdx.x;
  const float* src;
  unsigned short* dst;
  float* nrm;
  if (row < B_DIM) {
    src = x + (size_t)row * F_DIM;
    dst = xb + (size_t)row * F_DIM;
    nrm = x2 + row;
  } else {
    const int r = row - B_DIM;
    src = loc + (size_t)r * F_DIM;
    dst = locb + (size_t)r * F_DIM;
    nrm = c2 + r;
  }
  const int t = threadIdx.x;
  const float4 v = reinterpret_cast<const float4*>(src)[t];
  float ss = v.x * v.x + v.y * v.y + v.z * v.z + v.w * v.w;
  ushort4 o;
  o.x = f2bf(v.x); o.y = f2bf(v.y); o.z = f2bf(v.z); o.w = f2bf(v.w);
  reinterpret_cast<ushort4*>(dst)[t] = o;
#pragma unroll
  for (int m = 1; m <= 32; m <<= 1) ss += __shfl_xor(ss, m, 64);
  __shared__ float red[4];
  if ((t & 63) == 0) red[t >> 6] = ss;
  __syncthreads();
  if (t == 0) *nrm = red[0] + red[1] + red[2] + red[3];
}

// ---------------------------------------------------------------------------
// Fused: S = loc_bf16 @ x_bf16^T (MFMA), phi = exp(-sqrt(max(c2+x2-2S,0))/scale),
// P[slice][b][o] = sum_{c in 256-slice} phi[c][b] * w[o][c]   (no atomics).
//
// Tile: 256 c (M) x 128 b (N), BK=32; 4 waves in (cdir 2)x(bdir 2); each wave
// 128x64 via 8x4 grid of 16x16x32 MFMAs. LDS double-buffered with raw
// s_waitcnt vmcnt(6)/s_barrier prefetch (loads for step k+1 in flight across
// the barrier — never drain to 0 mid-loop).
//
// XCD swizzle: blockIdx&7 selects an XCD-owned 512-centroid stripe so the loc
// stripe (1 MB) stays L2-resident per XCD.
__global__ __launch_bounds__(256, 2) void rbf_fused(
    const unsigned short* __restrict__ locb,  // [C_DIM][F_DIM] bf16 bits
    const unsigned short* __restrict__ xb,    // [B_DIM][F_DIM] bf16 bits
    const float* __restrict__ c2,             // [C_DIM]
    const float* __restrict__ x2,             // [B_DIM]
    const float* __restrict__ scale,          // [C_DIM]
    const float* __restrict__ w,              // [O_DIM][C_DIM]
    float* __restrict__ P) {                  // [NSLICE][B_DIM][O_DIM]
  __shared__ alignas(16) unsigned short As[2 * 256 * 32];  // 32 KB (2 bufs)
  __shared__ alignas(16) unsigned short Bs[2 * 128 * 32];  // 16 KB (2 bufs)
  __shared__ alignas(16) float wlds[O_DIM * 256];          // 10 KB
  __shared__ alignas(16) float c2l[256];
  __shared__ alignas(16) float nisl[256];

  const int tid = threadIdx.x;
  const int wave = tid >> 6;
  const int lane = tid & 63;
  const int quad = lane >> 4;
  const int n15 = lane & 15;

  // XCD-aware mapping: g = XCD, cIdx in {2g, 2g+1} fastest, then bIdx.
  const int id = blockIdx.x;
  const int g = id & 7;
  const int j = id >> 3;
  const int cIdx = (g << 1) + (j & 1);   // 0..15
  const int bIdx = j >> 1;               // 0..63
  const int cBase = cIdx << 8;
  const int bBase = bIdx << 7;

  const int wcc = (wave >> 1) * 128;  // wave centroid offset in tile
  const int wbb = (wave & 1) * 64;    // wave batch offset in tile

  // Stage epilogue operands (lgkm-drained by first K-loop barrier).
  for (int i = tid; i < O_DIM * 256; i += 256)
    wlds[i] = w[(i >> 8) * C_DIM + cBase + (i & 255)];
  c2l[tid] = c2[cBase + tid];
  nisl[tid] = -1.0f / scale[cBase + tid];

  float x2v[4];
#pragma unroll
  for (int tj = 0; tj < 4; ++tj) x2v[tj] = x2[bBase + wbb + tj * 16 + n15];

  // Staging maps. A tile 256x32 (16 KB) = 16 chunks of 1 KB; wave handles 4.
  // B tile 128x32 (8 KB) = 8 chunks; wave handles 2. Within a chunk (16 rows
  // x 64 B): lane l -> row l>>2, physical 16-B slot l&3, global k-chunk
  // (l&3)^((l>>3)&3) (XOR swizzle; reader uses matching slot).
  const int rowIn = lane >> 2;
  const int colOff = ((lane & 3) ^ ((lane >> 3) & 3)) * 8;  // bf16 elems

  const unsigned short* aS0 = locb + (size_t)(cBase + wave * 64 + 0 + rowIn) * F_DIM + colOff;
  const unsigned short* aS1 = locb + (size_t)(cBase + wave * 64 + 16 + rowIn) * F_DIM + colOff;
  const unsigned short* aS2 = locb + (size_t)(cBase + wave * 64 + 32 + rowIn) * F_DIM + colOff;
  const unsigned short* aS3 = locb + (size_t)(cBase + wave * 64 + 48 + rowIn) * F_DIM + colOff;
  const unsigned short* bS0 = xb + (size_t)(bBase + wave * 32 + 0 + rowIn) * F_DIM + colOff;
  const unsigned short* bS1 = xb + (size_t)(bBase + wave * 32 + 16 + rowIn) * F_DIM + colOff;

#define ISSUE(p, k0)                                                                     \
  do {                                                                                   \
    __builtin_amdgcn_global_load_lds(                                                    \
        (const __attribute__((address_space(1))) void*)(aS0 + (k0)),                     \
        (__attribute__((address_space(3))) void*)&As[(p) * 8192 + (wave * 4 + 0) * 512], \
        16, 0, 0);                                                                       \
    __builtin_amdgcn_global_load_lds(                                                    \
        (const __attribute__((address_space(1))) void*)(aS1 + (k0)),                     \
        (__attribute__((address_space(3))) void*)&As[(p) * 8192 + (wave * 4 + 1) * 512], \
        16, 0, 0);                                                                       \
    __builtin_amdgcn_global_load_lds(                                                    \
        (const __attribute__((address_space(1))) void*)(aS2 + (k0)),                     \
        (__attribute__((address_space(3))) void*)&As[(p) * 8192 + (wave * 4 + 2) * 512], \
        16, 0, 0);                                                                       \
    __builtin_amdgcn_global_load_lds(                                                    \
        (const __attribute__((address_space(1))) void*)(aS3 + (k0)),                     \
        (__attribute__((address_space(3))) void*)&As[(p) * 8192 + (wave * 4 + 3) * 512], \
        16, 0, 0);                                                                       \
    __builtin_amdgcn_global_load_lds(                                                    \
        (const __attribute__((address_space(1))) void*)(bS0 + (k0)),                     \
        (__attribute__((address_space(3))) void*)&Bs[(p) * 4096 + (wave * 2 + 0) * 512], \
        16, 0, 0);                                                                       \
    __builtin_amdgcn_global_load_lds(                                                    \
        (const __attribute__((address_space(1))) void*)(bS1 + (k0)),                     \
        (__attribute__((address_space(3))) void*)&Bs[(p) * 4096 + (wave * 2 + 1) * 512], \
        16, 0, 0);                                                                       \
  } while (0)

  f32x4 acc[8][4];
  const f32x4 zero = {0.f, 0.f, 0.f, 0.f};
#pragma unroll
  for (int i = 0; i < 8; ++i)
#pragma unroll
    for (int jj = 0; jj < 4; ++jj) acc[i][jj] = zero;

  const int swA = (quad ^ ((n15 >> 1) & 3)) * 8;

  auto compute = [&](int p) {
    const unsigned short* Ab = &As[p * 8192];
    const unsigned short* Bb = &Bs[p * 4096];
    bf16x8 af[8], bfr[4];
#pragma unroll
    for (int ti = 0; ti < 8; ++ti)
      af[ti] = __builtin_bit_cast(
          bf16x8, *(const ushort8*)&Ab[(wcc + ti * 16 + n15) * 32 + swA]);
#pragma unroll
    for (int tj = 0; tj < 4; ++tj)
      bfr[tj] = __builtin_bit_cast(
          bf16x8, *(const ushort8*)&Bb[(wbb + tj * 16 + n15) * 32 + swA]);
#pragma unroll
    for (int ti = 0; ti < 8; ++ti)
#pragma unroll
      for (int tj = 0; tj < 4; ++tj)
        acc[ti][tj] = __builtin_amdgcn_mfma_f32_16x16x32_bf16(
            af[ti], bfr[tj], acc[ti][tj], 0, 0, 0);
  };

  // Quiesce vm counter so in-loop vmcnt(N) semantics are exact.
  asm volatile("s_waitcnt vmcnt(0)" ::: "memory");
  ISSUE(0, 0);
  for (int k0 = 0; k0 < F_DIM; k0 += 64) {
    if (k0 + 32 < F_DIM) {
      ISSUE(1, k0 + 32);
      asm volatile("s_waitcnt vmcnt(6)\ns_barrier" ::: "memory");
    } else {
      asm volatile("s_waitcnt vmcnt(0)\ns_barrier" ::: "memory");
    }
    compute(0);
    asm volatile("s_waitcnt lgkmcnt(0)\ns_barrier" ::: "memory");
    if (k0 + 64 < F_DIM) {
      ISSUE(0, k0 + 64);
      asm volatile("s_waitcnt vmcnt(6)\ns_barrier" ::: "memory");
    } else {
      asm volatile("s_waitcnt vmcnt(0)\ns_barrier" ::: "memory");
    }
    compute(1);
    asm volatile("s_waitcnt lgkmcnt(0)\ns_barrier" ::: "memory");
  }

  // ---- epilogue ----
  // acc[ti][tj][r]: c_local = wcc+ti*16+quad*4+r, b_local = wbb+tj*16+n15.
  float partial[4][O_DIM];
#pragma unroll
  for (int tj = 0; tj < 4; ++tj)
#pragma unroll
    for (int o = 0; o < O_DIM; ++o) partial[tj][o] = 0.f;

#pragma unroll
  for (int ti = 0; ti < 8; ++ti) {
    const int clq = wcc + ti * 16 + quad * 4;
    const f32x4 c24 = *(const f32x4*)&c2l[clq];
    const f32x4 ns4 = *(const f32x4*)&nisl[clq];
    float phi[4][4];  // [tj][r]
#pragma unroll
    for (int tj = 0; tj < 4; ++tj)
#pragma unroll
      for (int r = 0; r < 4; ++r) {
        const float s = acc[ti][tj][r];
        const float sq = fmaxf(x2v[tj] + c24[r] - 2.0f * s, 0.0f);
        phi[tj][r] = __expf(sqrtf(sq) * ns4[r]);
      }
#pragma unroll
    for (int o = 0; o < O_DIM; ++o) {
      const f32x4 w4 = *(const f32x4*)&wlds[o * 256 + clq];
#pragma unroll
      for (int tj = 0; tj < 4; ++tj)
#pragma unroll
        for (int r = 0; r < 4; ++r)
          partial[tj][o] = fmaf(phi[tj][r], w4[r], partial[tj][o]);
    }
  }

  // reduce over the 4 quads (lanes ^16, ^32 share the same batch index)
#pragma unroll
  for (int tj = 0; tj < 4; ++tj)
#pragma unroll
    for (int o = 0; o < O_DIM; ++o) {
      float v = partial[tj][o];
      v += __shfl_xor(v, 16, 64);
      v += __shfl_xor(v, 32, 64);
      partial[tj][o] = v;
    }

  // Cross-wave (c-halves) reduce via LDS (alias dead As buf0), then store.
  float* red = reinterpret_cast<float*>(As);  // 1280 floats, region is dead
  if (wcc == 0 && quad == 0) {
#pragma unroll
    for (int tj = 0; tj < 4; ++tj)
#pragma unroll
      for (int o = 0; o < O_DIM; ++o)
        red[(wbb + tj * 16 + n15) * O_DIM + o] = partial[tj][o];
  }
  __syncthreads();
  if (wcc == 128 && quad == 0) {
#pragma unroll
    for (int tj = 0; tj < 4; ++tj)
#pragma unroll
      for (int o = 0; o < O_DIM; ++o)
        red[(wbb + tj * 16 + n15) * O_DIM + o] += partial[tj][o];
  }
  __syncthreads();
  float* Pdst = P + (size_t)cIdx * (B_DIM * O_DIM) + (size_t)bBase * O_DIM;
  for (int i = tid; i < 128 * O_DIM; i += 256) Pdst[i] = red[i];
}

// ---------------------------------------------------------------------------
// out[b][o] = sum_k P[k][b][o]
__global__ __launch_bounds__(256) void reduce_partials(const float* __restrict__ P,
                                                       float* __restrict__ out) {
  const int i = blockIdx.x * 256 + threadIdx.x;  // 0 .. B_DIM*O_DIM-1
  float s = 0.f;
#pragma unroll
  for (int k = 0; k < NSLICE; ++k) s += P[(size_t)k * (B_DIM * O_DIM) + i];
  out[i] = s;
}

// ---------------------------------------------------------------------------
extern "C" void kernel_launch(void* const* d_in, const int* in_sizes, int n_in,
                              void* d_out, int out_size, void* d_ws, size_t ws_size,
                              hipStream_t stream) {
  const float* x = (const float*)d_in[0];      // [8192,1024]
  const float* loc = (const float*)d_in[1];    // [4096,1024]
  const float* scale = (const float*)d_in[2];  // [4096]
  const float* w = (const float*)d_in[3];      // [10,4096]
  float* out = (float*)d_out;                  // [8192,10]

  // workspace layout (~30.3 MB)
  char* ws = (char*)d_ws;
  unsigned short* xb = (unsigned short*)(ws);                              // 16 MB
  unsigned short* locb = (unsigned short*)(ws + (size_t)16 * 1024 * 1024); // 8 MB
  float* x2 = (float*)(ws + (size_t)24 * 1024 * 1024);                    // 32 KB
  float* c2 = (float*)(ws + (size_t)24 * 1024 * 1024 + 64 * 1024);        // 16 KB
  float* P = (float*)(ws + (size_t)25 * 1024 * 1024);                     // 5.24 MB

  prep_merged<<<B_DIM + C_DIM, 256, 0, stream>>>(x, loc, xb, locb, x2, c2);

  rbf_fused<<<NSLICE * 64, 256, 0, stream>>>(locb, xb, c2, x2, scale, w, P);

  reduce_partials<<<(B_DIM * O_DIM) / 256, 256, 0, stream>>>(P, out);
}